// Round 8
// baseline (61.163 us; speedup 1.0000x reference)
//
#include <hip/hip_runtime.h>
#include <hip/hip_bf16.h>
#include <stdint.h>

#define LL 2048   // sequence length
#define NB 16     // batch
#define DD 256    // din = dout
#define NT2 16    // K-tiles (2048/128 bytes) in agg

typedef __bf16 bf16x8 __attribute__((ext_vector_type(8)));
typedef float f32x4 __attribute__((ext_vector_type(4)));
typedef int i32x4 __attribute__((ext_vector_type(4)));
typedef int i32x8 __attribute__((ext_vector_type(8)));
union Frag8 { i32x8 v8; i32x4 v4[2]; };

__device__ __forceinline__ unsigned short f2bf(float f) {
    __hip_bfloat16 h = __float2bfloat16(f);   // RNE
    return *reinterpret_cast<unsigned short*>(&h);
}

__device__ __forceinline__ float bf2f(unsigned short v) {
    return __uint_as_float(((uint32_t)v) << 16);
}

// ---- fp8 e4m3fn helpers -----------------------------------------------------
#if __has_builtin(__builtin_amdgcn_cvt_pk_fp8_f32)
__device__ __forceinline__ uint32_t pk4fp8(float a, float b, float c, float d) {
    int r = 0;
    r = __builtin_amdgcn_cvt_pk_fp8_f32(a, b, r, false);
    r = __builtin_amdgcn_cvt_pk_fp8_f32(c, d, r, true);
    return (uint32_t)r;
}
#else
__device__ __forceinline__ uint32_t f2fp8_1(float f) {
    uint32_t u = __float_as_uint(f);
    uint32_t s = (u >> 24) & 0x80u;
    uint32_t au = u & 0x7FFFFFFFu;
    float af = __uint_as_float(au);
    if (af >= 448.0f) return s | 0x7Eu;
    if (af < 0x1p-6f) {
        uint32_t q = (uint32_t)rintf(af * 512.0f);
        return s | q;
    }
    uint32_t r = au + (0x7FFFFu + ((au >> 20) & 1u));
    uint32_t e8 = (r >> 23) - 120u;
    return s | (e8 << 3) | ((r >> 20) & 7u);
}
__device__ __forceinline__ uint32_t pk4fp8(float a, float b, float c, float d) {
    return f2fp8_1(a) | (f2fp8_1(b) << 8) | (f2fp8_1(c) << 16) | (f2fp8_1(d) << 24);
}
#endif

__device__ __forceinline__ float fp8tof(uint32_t b) {
    uint32_t s = (b & 0x80u) << 24;
    uint32_t e = (b >> 3) & 15u, m = b & 7u;
    float v = (e == 0) ? (float)m * 0x1p-9f
            : __uint_as_float(((e + 120u) << 23) | (m << 20));
    return __uint_as_float(__float_as_uint(v) | s);
}

__device__ __forceinline__ void gload16(const void* g, void* l) {
    __builtin_amdgcn_global_load_lds(
        (const __attribute__((address_space(1))) void*)g,
        (__attribute__((address_space(3))) void*)l,
        16, 0, 0);
}

#define DSREAD(dst, off) asm volatile("ds_read_b128 %0, %1" : "=v"(dst) : "v"(off))

// ---------------------------------------------------------------------------
// Kernel 1: degree -> dinv, plus graph f32 -> fp8 e4m3 (values exactly 0/1)
// ---------------------------------------------------------------------------
__global__ __launch_bounds__(256) void prep_graph(
        const float* __restrict__ graph, float* __restrict__ dinv,
        uint8_t* __restrict__ gq) {
    int r = blockIdx.x;
    int t = threadIdx.x;
    const float4* row = (const float4*)(graph + (size_t)r * LL);
    float4 v0 = row[t * 2 + 0];
    float4 v1 = row[t * 2 + 1];
    float s = v0.x + v0.y + v0.z + v0.w + v1.x + v1.y + v1.z + v1.w;

    uint32_t lo = (v0.x != 0.f ? 0x38u : 0u) | ((v0.y != 0.f ? 0x38u : 0u) << 8)
                | ((v0.z != 0.f ? 0x38u : 0u) << 16) | ((v0.w != 0.f ? 0x38u : 0u) << 24);
    uint32_t hi = (v1.x != 0.f ? 0x38u : 0u) | ((v1.y != 0.f ? 0x38u : 0u) << 8)
                | ((v1.z != 0.f ? 0x38u : 0u) << 16) | ((v1.w != 0.f ? 0x38u : 0u) << 24);
    *(uint2*)(gq + (size_t)r * LL + t * 8) = make_uint2(lo, hi);

    #pragma unroll
    for (int off = 32; off > 0; off >>= 1) s += __shfl_down(s, off, 64);
    __shared__ float red[4];
    if ((t & 63) == 0) red[t >> 6] = s;
    __syncthreads();
    if (t == 0) {
        float deg = red[0] + red[1] + red[2] + red[3] + 1.0f;  // + self loop
        dinv[r] = 1.0f / sqrtf(deg);
    }
}

// ---------------------------------------------------------------------------
// Kernel 2: Wt[o][d] = bf16(W[d][o])
// ---------------------------------------------------------------------------
__global__ __launch_bounds__(256) void prep_w(
        const float* __restrict__ W, unsigned short* __restrict__ Wt) {
    int tid = blockIdx.x * 256 + threadIdx.x;
    int d = tid >> 8, o = tid & 255;
    Wt[o * DD + d] = f2bf(W[tid]);
}

// ---------------------------------------------------------------------------
// Kernel 3 (R4-proven v1): Pq[b*256+o][m] = fp8( dinv[m] * sum_d x*W )
// 256x2 blocks, 256 thr, 4 waves 2x2, 128x128 tile, K=256 in 4 steps.
// ---------------------------------------------------------------------------
__global__ __launch_bounds__(256) void linear_kernel(
        const float* __restrict__ x, const unsigned short* __restrict__ Wt,
        const float* __restrict__ dinv, uint8_t* __restrict__ Pq) {
    __shared__ __align__(16) unsigned short Al[128][64];
    __shared__ __align__(16) unsigned short Bl[128][64];
    int t = threadIdx.x;
    int w = t >> 6, ln = t & 63;
    int m0 = blockIdx.x * 128;
    int n0 = blockIdx.y * 128;
    int b  = m0 >> 11;
    int ml0 = m0 & (LL - 1);
    int wm = w >> 1, wn = w & 1;
    int lr = ln & 15, lg = ln >> 4;

    f32x4 acc[4][4] = {};

    for (int k0 = 0; k0 < DD; k0 += 64) {
        #pragma unroll
        for (int it = 0; it < 8; ++it) {
            int c = it * 256 + t;
            int row = c >> 4, col = (c & 15) * 4;
            float4 v = *(const float4*)(x + (size_t)(m0 + row) * DD + k0 + col);
            *(ushort4*)(&Al[row][col]) =
                make_ushort4(f2bf(v.x), f2bf(v.y), f2bf(v.z), f2bf(v.w));
        }
        #pragma unroll
        for (int it = 0; it < 4; ++it) {
            int c = it * 256 + t;
            const unsigned short* g = Wt + (size_t)(n0 + (c >> 3)) * DD + k0 + (c & 7) * 8;
            unsigned short* lp = &Bl[0][0] + (size_t)(it * 256 + w * 64) * 8;
            gload16(g, lp);
        }
        __syncthreads();
        #pragma unroll
        for (int kk = 0; kk < 64; kk += 32) {
            bf16x8 af[4], bq[4];
            #pragma unroll
            for (int i = 0; i < 4; ++i)
                af[i] = *(const bf16x8*)&Al[wm * 64 + i * 16 + lr][kk + lg * 8];
            #pragma unroll
            for (int j = 0; j < 4; ++j)
                bq[j] = *(const bf16x8*)&Bl[wn * 64 + j * 16 + lr][kk + lg * 8];
            #pragma unroll
            for (int i = 0; i < 4; ++i)
                #pragma unroll
                for (int j = 0; j < 4; ++j)
                    acc[i][j] = __builtin_amdgcn_mfma_f32_16x16x32_bf16(
                        af[i], bq[j], acc[i][j], 0, 0, 0);
        }
        __syncthreads();
    }

    #pragma unroll
    for (int i = 0; i < 4; ++i) {
        int ml = ml0 + wm * 64 + i * 16 + lg * 4;
        float4 dv = *(const float4*)(dinv + ml);
        #pragma unroll
        for (int j = 0; j < 4; ++j) {
            int o = n0 + wn * 64 + j * 16 + lr;
            uint32_t pk = pk4fp8(dv.x * acc[i][j][0], dv.y * acc[i][j][1],
                                 dv.z * acc[i][j][2], dv.w * acc[i][j][3]);
            *(uint32_t*)(Pq + ((size_t)(b * DD + o)) * LL + ml) = pk;
        }
    }
}

// ---------------------------------------------------------------------------
// Kernel 4 v7: agg = gq @ Pq^T in MX-fp8 (scale=1.0). R3-proven data mapping
// (BM=128, BN=256, BK=128B, 8 waves 2Mx4N, 3-buf ring, gap-2 staging with
// counted vmcnt(6)), but ONE barrier + ONE lgkmcnt(0) per iter instead of
// R3's 4 barriers + 2 lgkm drains. No cross-iter frag registers (R6/R7's
// S[2] pipeline suspected of spill-to-scratch corruption — rule #18/#20).
// Epilogue: out = relu(dinv[l]*(S + Pq[n'][l]) + bias[o]) + x
// ---------------------------------------------------------------------------
__global__ __launch_bounds__(512, 2) void agg_kernel(
        const uint8_t* __restrict__ gq, const uint8_t* __restrict__ Pq,
        const float* __restrict__ dinv, const float* __restrict__ bias,
        const float* __restrict__ x, float* __restrict__ out) {
    // per buffer: A 128x128B (16KB) + B 256x128B (32KB) = 48KB; x3 = 144 KiB
    __shared__ __align__(16) unsigned char lds[3 * 49152];

    const int t = threadIdx.x;
    const int w = t >> 6, ln = t & 63;
    const int wm = w >> 2, wn = w & 3;          // 2 x 4 wave grid
    const int lr = ln & 15, lg = ln >> 4;
    const int s7 = lr & 7;

    // XCD swizzle: 32 consecutive wgs/XCD = 16 l-tiles x 2 n'-tiles
    int bid = blockIdx.x;
    int wg = (bid & 7) * 32 + (bid >> 3);
    const int l0 = (wg & 15) * 128;
    const int n0 = (wg >> 4) * 256;

    // staging source (pre-swizzled global: slot_src = slot_lin ^ (row&7))
    const int rt = t >> 3;                      // 0..63
    const int st = (t & 7) ^ (rt & 7);
    const uint8_t* a0 = gq + (size_t)(l0 + rt) * LL + st * 16;
    const uint8_t* a1 = a0 + (size_t)64 * LL;
    const uint8_t* b0 = Pq + (size_t)(n0 + rt) * LL + st * 16;
    const uint8_t* b1 = b0 + (size_t)64 * LL;
    const uint8_t* b2 = b0 + (size_t)128 * LL;
    const uint8_t* b3 = b0 + (size_t)192 * LL;
    const int wd = w * 1024;                    // wave-uniform LDS dst (bytes)

    #define STAGE(bufbase, ko) { \
        gload16(a0 + (ko), lds + (bufbase) +         wd); \
        gload16(a1 + (ko), lds + (bufbase) +  8192 + wd); \
        gload16(b0 + (ko), lds + (bufbase) + 16384 + wd); \
        gload16(b1 + (ko), lds + (bufbase) + 24576 + wd); \
        gload16(b2 + (ko), lds + (bufbase) + 32768 + wd); \
        gload16(b3 + (ko), lds + (bufbase) + 40960 + wd); }

    f32x4 acc[4][4] = {};

    // prologue: stage tiles 0,1 into bufs 0,1. vmcnt(6): tile 0's 6 landed.
    STAGE(0, 0);
    STAGE(49152, 128);
    asm volatile("s_waitcnt vmcnt(6)" ::: "memory");
    __builtin_amdgcn_s_barrier();

    int cbi = 0;   // buffer index of tile tt
    for (int tt = 0; tt < NT2; ++tt) {
        const int cb = cbi * 49152;

        // issue ALL 16 ds_reads of tile tt (identical offsets to R3-proven)
        Frag8 bq[4], fa[2], fc[2];
        #pragma unroll
        for (int j = 0; j < 4; ++j)
            #pragma unroll
            for (int h = 0; h < 2; ++h) {
                int off = cb + 16384 + (wn * 64 + j * 16 + lr) * 128
                        + (((lg * 2 + h) ^ s7) << 4);
                DSREAD(bq[j].v4[h], off);
            }
        #pragma unroll
        for (int i = 0; i < 2; ++i)
            #pragma unroll
            for (int h = 0; h < 2; ++h) {
                int off = cb + (wm * 64 + i * 16 + lr) * 128
                        + (((lg * 2 + h) ^ s7) << 4);
                DSREAD(fa[i].v4[h], off);
            }
        #pragma unroll
        for (int i = 0; i < 2; ++i)
            #pragma unroll
            for (int h = 0; h < 2; ++h) {
                int off = cb + (wm * 64 + (i + 2) * 16 + lr) * 128
                        + (((lg * 2 + h) ^ s7) << 4);
                DSREAD(fc[i].v4[h], off);
            }

        // stage tile tt+2 (gap-2: read 2 iters later; vmcnt(6) discipline)
        if (tt + 2 < NT2) {
            int sbi = cbi + 2; if (sbi >= 3) sbi -= 3;
            STAGE(sbi * 49152, (tt + 2) * 128);
        }

        asm volatile("s_waitcnt lgkmcnt(0)" ::: "memory");
        __builtin_amdgcn_sched_barrier(0);
        __builtin_amdgcn_s_setprio(1);
        #pragma unroll
        for (int i = 0; i < 2; ++i)
            #pragma unroll
            for (int j = 0; j < 4; ++j) {
                acc[i][j] = __builtin_amdgcn_mfma_scale_f32_16x16x128_f8f6f4(
                    fa[i].v8, bq[j].v8, acc[i][j], 0, 0, 0, 127, 0, 127);
                acc[i + 2][j] = __builtin_amdgcn_mfma_scale_f32_16x16x128_f8f6f4(
                    fc[i].v8, bq[j].v8, acc[i + 2][j], 0, 0, 0, 127, 0, 127);
            }
        __builtin_amdgcn_s_setprio(0);
        __builtin_amdgcn_sched_barrier(0);
        // counted drain: everything issued before THIS iter has landed =>
        // tile tt+1 (staged at iter tt-1) is complete before the barrier.
        asm volatile("s_waitcnt vmcnt(6)" ::: "memory");
        __builtin_amdgcn_s_barrier();

        cbi = (cbi == 2) ? 0 : cbi + 1;
    }

    // ================= epilogue =================
    const int b = n0 >> 8;
    #pragma unroll
    for (int j = 0; j < 4; ++j) {
        int np = n0 + wn * 64 + j * 16 + lr;
        int o = np & (DD - 1);
        float bo = bias[o];
        #pragma unroll
        for (int i = 0; i < 4; ++i) {
            int lrow = l0 + wm * 64 + i * 16 + lg * 4;
            float4 dv = *(const float4*)(dinv + lrow);
            uchar4 pv = *(const uchar4*)(Pq + (size_t)np * LL + lrow);
            float dva[4] = {dv.x, dv.y, dv.z, dv.w};
            float pva[4] = {fp8tof(pv.x), fp8tof(pv.y), fp8tof(pv.z), fp8tof(pv.w)};
            #pragma unroll
            for (int r = 0; r < 4; ++r) {
                float aggv = dva[r] * (acc[i][j][r] + pva[r]) + bo;
                float rl = fmaxf(aggv, 0.0f);
                size_t oi = ((size_t)(b * LL + lrow + r)) * DD + o;
                out[oi] = rl + x[oi];
            }
        }
    }
}

// ---------------------------------------------------------------------------
extern "C" void kernel_launch(void* const* d_in, const int* in_sizes, int n_in,
                              void* d_out, int out_size, void* d_ws, size_t ws_size,
                              hipStream_t stream) {
    const float* x     = (const float*)d_in[0];   // [16,2048,256]
    const float* graph = (const float*)d_in[1];   // [1,2048,2048]
    const float* W     = (const float*)d_in[2];   // [256,256]
    const float* bias  = (const float*)d_in[3];   // [256]
    float* out = (float*)d_out;

    char* ws = (char*)d_ws;
    float*          dinv = (float*)ws;                                   // 8 KB
    uint8_t*        gq   = (uint8_t*)(ws + 8192);                        // 4 MB
    unsigned short* Wt   = (unsigned short*)(ws + 8192 + 4194304);       // 128 KB
    uint8_t*        Pq   = (uint8_t*)(ws + 8192 + 4194304 + 131072);     // 8 MB

    prep_graph<<<LL, 256, 0, stream>>>(graph, dinv, gq);
    prep_w<<<DD, 256, 0, stream>>>(W, Wt);
    linear_kernel<<<dim3((NB * LL) / 128, DD / 128), 256, 0, stream>>>(x, Wt, dinv, Pq);
    agg_kernel<<<256, 512, 0, stream>>>(gq, Pq, dinv, bias, x, out);
}